// Round 1
// baseline (202.685 us; speedup 1.0000x reference)
//
#include <hip/hip_runtime.h>

// ---------------------------------------------------------------------------
// PhysicsGraphNeuralODEFunc: out[b,i] = (x@L^T)[b,i] + quad_mean[b] + cubic_mean[b]
//                                       + (i==0)*cT[b] + (i==1)*cH[b]
// where quad_mean[b] = sum_h relu(x@qW1 + qb1)[b,h] * colmean(qW2)[h] + mean(qb2)
// All three big matmuls fused into ONE bf16-MFMA GEMM: x(16384x512) @ WcatT^T,
// WcatT (1536x512) = [ L | qW1^T | cW1^T ] stored n-major (row n, col k).
// ---------------------------------------------------------------------------

#define OMEGA_F 0.5235987755982988f

typedef __attribute__((ext_vector_type(8))) short short8;
typedef __attribute__((ext_vector_type(4))) float f32x4;

__device__ __forceinline__ unsigned short f2bf(float f) {
  union { float f; unsigned int u; } a;
  a.f = f;
  unsigned int u = a.u;
  return (unsigned short)((u + 0x7fffu + ((u >> 16) & 1u)) >> 16);
}

// ---- prep: build WcatT (1536 x 512, bf16, n-major) -------------------------
__global__ void build_wcat(const float* __restrict__ fc, const float* __restrict__ qW1,
                           const float* __restrict__ cW1, const float* __restrict__ t,
                           unsigned short* __restrict__ WT) {
  int idx = blockIdx.x * 256 + threadIdx.x;  // 0 .. 1536*512-1
  int n = idx >> 9;
  int k = idx & 511;
  float v;
  if (n < 512) {
    // WcatT[n][k] = L[n][k] = fc[n,k,0] + fc[n,k,1]*cos(th) + fc[n,k,2]*sin(th)
    //                         + fc[n,k,3]*cos(2th) + fc[n,k,4]*sin(2th)
    float th = OMEGA_F * t[0];
    float s1, c1, s2, c2;
    sincosf(th, &s1, &c1);
    sincosf(2.0f * th, &s2, &c2);
    const float* p = fc + ((size_t)n * 512 + k) * 5;
    v = p[0] + p[1] * c1 + p[2] * s1 + p[3] * c2 + p[4] * s2;
  } else if (n < 1024) {
    v = qW1[(size_t)k * 512 + (n - 512)];   // transpose of quad_W1 (D,HID)
  } else {
    v = cW1[(size_t)k * 512 + (n - 1024)];  // transpose of cubic_W1
  }
  WT[idx] = f2bf(v);
}

// ---- prep: col-means of W2 (i.e. row means, W2 is (HID,D) row-major) -------
__global__ void build_means(const float* __restrict__ qW2, const float* __restrict__ cW2,
                            const float* __restrict__ qb2, const float* __restrict__ cb2,
                            float* __restrict__ qw2m, float* __restrict__ cw2m,
                            float* __restrict__ b2m) {
  int b = blockIdx.x, tdx = threadIdx.x;
  if (b < 4) {
    const float* W = (b < 2) ? qW2 : cW2;
    float* o = (b < 2) ? qw2m : cw2m;
    int h = (b & 1) * 256 + tdx;
    const float4* row = (const float4*)(W + (size_t)h * 512);
    float s = 0.f;
    for (int i = 0; i < 128; ++i) { float4 v = row[i]; s += (v.x + v.y) + (v.z + v.w); }
    o[h] = s * (1.0f / 512.0f);
  } else {
    __shared__ float sm[256];
    sm[tdx] = qb2[tdx] + qb2[tdx + 256];
    __syncthreads();
    for (int w = 128; w > 0; w >>= 1) { if (tdx < w) sm[tdx] += sm[tdx + w]; __syncthreads(); }
    if (tdx == 0) b2m[0] = sm[0] * (1.0f / 512.0f);
    __syncthreads();
    sm[tdx] = cb2[tdx] + cb2[tdx + 256];
    __syncthreads();
    for (int w = 128; w > 0; w >>= 1) { if (tdx < w) sm[tdx] += sm[tdx + w]; __syncthreads(); }
    if (tdx == 0) b2m[1] = sm[0] * (1.0f / 512.0f);
  }
}

// ---- enso: per-row tiny MLPs (5->32->1), ~6 MFLOP total --------------------
__global__ void enso_kernel(const float* __restrict__ x,
                            const float* __restrict__ tW1, const float* __restrict__ tb1,
                            const float* __restrict__ tW2, const float* __restrict__ tb2,
                            const float* __restrict__ hW1, const float* __restrict__ hb1,
                            const float* __restrict__ hW2, const float* __restrict__ hb2,
                            float* __restrict__ cT, float* __restrict__ cH) {
  int b = blockIdx.x * 256 + threadIdx.x;  // 16384 rows
  float T = x[(size_t)b * 512];
  float H = x[(size_t)b * 512 + 1];
  float fT[5] = {T, H, T * T, T * H, T * T * T};
  float fH[5] = {T, H, T * T, T * H, T * H * H};
  float sT = tb2[0], sH = hb2[0];
#pragma unroll 4
  for (int e = 0; e < 32; ++e) {
    float a1 = tb1[e], a2 = hb1[e];
#pragma unroll
    for (int f = 0; f < 5; ++f) {
      a1 += fT[f] * tW1[f * 32 + e];
      a2 += fH[f] * hW1[f * 32 + e];
    }
    sT += fmaxf(a1, 0.f) * tW2[e];
    sH += fmaxf(a2, 0.f) * hW2[e];
  }
  cT[b] = sT;
  cH[b] = sH;
}

// ---- convert x to bf16 -----------------------------------------------------
__global__ void convert_x(const float4* __restrict__ x, uint2* __restrict__ xb) {
  int i = blockIdx.x * 256 + threadIdx.x;  // 8388608/4 elements
  float4 v = x[i];
  uint2 r;
  r.x = (unsigned)f2bf(v.x) | ((unsigned)f2bf(v.y) << 16);
  r.y = (unsigned)f2bf(v.z) | ((unsigned)f2bf(v.w) << 16);
  xb[i] = r;
}

// ---- main GEMM: C(16384x1536) = A(16384x512) * WcatT^T ---------------------
// 128x128 tiles, BK=32, 4 waves (2x2), each wave 64x64 = 4x4 MFMA 16x16x32 frags.
// Region epilogue: n<512 -> store to out; else relu(.+b1)*w2m row-reduce -> atomicAdd rowadd.
__global__ __launch_bounds__(256) void gemm_kernel(
    const unsigned short* __restrict__ A,   // 16384 x 512 bf16
    const unsigned short* __restrict__ Bt,  // 1536 x 512 bf16 (n-major)
    const float* __restrict__ qb1, const float* __restrict__ cb1,
    const float* __restrict__ qw2m, const float* __restrict__ cw2m,
    float* __restrict__ out, float* __restrict__ rowadd) {
  __shared__ unsigned short As[128 * 32];
  __shared__ unsigned short Bs[128 * 32];
  const int tid = threadIdx.x;
  const int lane = tid & 63;
  const int wave = tid >> 6;
  const int wm = wave & 1;
  const int wn = wave >> 1;
  const int m_base = blockIdx.x * 128;
  const int n_base = blockIdx.y * 128;
  const int lrow = lane & 15;
  const int lk = (lane >> 4) * 8;

  f32x4 acc[4][4];
#pragma unroll
  for (int i = 0; i < 4; ++i)
#pragma unroll
    for (int j = 0; j < 4; ++j) acc[i][j] = (f32x4){0.f, 0.f, 0.f, 0.f};

  for (int k0 = 0; k0 < 512; k0 += 32) {
#pragma unroll
    for (int u = 0; u < 2; ++u) {
      int f = tid + u * 256;
      int row = f >> 2;
      int cg = (f & 3) * 8;
      *(uint4*)(&As[row * 32 + cg]) =
          *(const uint4*)(&A[(size_t)(m_base + row) * 512 + k0 + cg]);
      *(uint4*)(&Bs[row * 32 + cg]) =
          *(const uint4*)(&Bt[(size_t)(n_base + row) * 512 + k0 + cg]);
    }
    __syncthreads();
    short8 af[4], bfr[4];
#pragma unroll
    for (int i = 0; i < 4; ++i)
      af[i] = *(const short8*)(&As[(wm * 64 + i * 16 + lrow) * 32 + lk]);
#pragma unroll
    for (int j = 0; j < 4; ++j)
      bfr[j] = *(const short8*)(&Bs[(wn * 64 + j * 16 + lrow) * 32 + lk]);
#pragma unroll
    for (int i = 0; i < 4; ++i)
#pragma unroll
      for (int j = 0; j < 4; ++j)
        acc[i][j] = __builtin_amdgcn_mfma_f32_16x16x32_bf16(af[i], bfr[j], acc[i][j], 0, 0, 0);
    __syncthreads();
  }

  // C/D layout: col = lane&15, row = (lane>>4)*4 + reg  (verified m89/m91)
  const int rbase = m_base + wm * 64 + (lane >> 4) * 4;
  if (blockIdx.y < 4) {
    // linear region: direct store
#pragma unroll
    for (int i = 0; i < 4; ++i)
#pragma unroll
      for (int j = 0; j < 4; ++j) {
        int col = n_base + wn * 64 + j * 16 + lrow;
#pragma unroll
        for (int r = 0; r < 4; ++r)
          out[(size_t)(rbase + i * 16 + r) * 512 + col] = acc[i][j][r];
      }
  } else {
    const bool isq = (blockIdx.y < 8);
    const float* b1 = isq ? qb1 : cb1;
    const float* w2m = isq ? qw2m : cw2m;
    const int cb0 = n_base - (isq ? 512 : 1024) + wn * 64 + lrow;
    float rs[4][4];
#pragma unroll
    for (int i = 0; i < 4; ++i)
#pragma unroll
      for (int r = 0; r < 4; ++r) rs[i][r] = 0.f;
#pragma unroll
    for (int j = 0; j < 4; ++j) {
      int col = cb0 + j * 16;
      float bb = b1[col];
      float ww = w2m[col];
#pragma unroll
      for (int i = 0; i < 4; ++i)
#pragma unroll
        for (int r = 0; r < 4; ++r)
          rs[i][r] += fmaxf(acc[i][j][r] + bb, 0.f) * ww;
    }
#pragma unroll
    for (int i = 0; i < 4; ++i)
#pragma unroll
      for (int r = 0; r < 4; ++r) {
        float v = rs[i][r];
        v += __shfl_xor(v, 1, 64);
        v += __shfl_xor(v, 2, 64);
        v += __shfl_xor(v, 4, 64);
        v += __shfl_xor(v, 8, 64);
        if (lrow == 0) atomicAdd(&rowadd[rbase + i * 16 + r], v);
      }
  }
}

// ---- finalize: out += rowadd + b2means + enso corrections ------------------
__global__ void finalize(float* __restrict__ out, const float* __restrict__ rowadd,
                         const float* __restrict__ b2m, const float* __restrict__ cT,
                         const float* __restrict__ cH) {
  int idx = blockIdx.x * 256 + threadIdx.x;  // over 2097152 float4s
  int row = idx >> 7;                        // 128 float4 per row
  int c4 = idx & 127;
  float add = rowadd[row] + b2m[0] + b2m[1];
  float4 v = ((float4*)out)[idx];
  v.x += add; v.y += add; v.z += add; v.w += add;
  if (c4 == 0) { v.x += cT[row]; v.y += cH[row]; }
  ((float4*)out)[idx] = v;
}

extern "C" void kernel_launch(void* const* d_in, const int* in_sizes, int n_in,
                              void* d_out, int out_size, void* d_ws, size_t ws_size,
                              hipStream_t stream) {
  const float* x   = (const float*)d_in[0];
  const float* t   = (const float*)d_in[1];
  const float* fc  = (const float*)d_in[2];
  const float* qW1 = (const float*)d_in[3];
  const float* qb1 = (const float*)d_in[4];
  const float* qW2 = (const float*)d_in[5];
  const float* qb2 = (const float*)d_in[6];
  const float* cW1 = (const float*)d_in[7];
  const float* cb1 = (const float*)d_in[8];
  const float* cW2 = (const float*)d_in[9];
  const float* cb2 = (const float*)d_in[10];
  const float* tW1 = (const float*)d_in[11];
  const float* tb1 = (const float*)d_in[12];
  const float* tW2 = (const float*)d_in[13];
  const float* tb2 = (const float*)d_in[14];
  const float* hW1 = (const float*)d_in[15];
  const float* hb1 = (const float*)d_in[16];
  const float* hW2 = (const float*)d_in[17];
  const float* hb2 = (const float*)d_in[18];
  float* out = (float*)d_out;

  // workspace layout (bytes); total ~18.6 MB
  char* ws = (char*)d_ws;
  unsigned short* WT = (unsigned short*)(ws);              // 1536*512*2   = 1,572,864
  unsigned short* xb = (unsigned short*)(ws + 1572864);    // 16384*512*2  = 16,777,216
  float* qw2m   = (float*)(ws + 18350080);                 // 512*4
  float* cw2m   = (float*)(ws + 18352128);                 // 512*4
  float* b2m    = (float*)(ws + 18354176);                 // 2*4 (pad)
  float* cT     = (float*)(ws + 18354432);                 // 16384*4
  float* cH     = (float*)(ws + 18419968);                 // 16384*4
  float* rowadd = (float*)(ws + 18485504);                 // 16384*4 -> ends 18,551,040

  hipMemsetAsync(rowadd, 0, 16384 * sizeof(float), stream);
  build_wcat<<<3072, 256, 0, stream>>>(fc, qW1, cW1, t, WT);
  build_means<<<5, 256, 0, stream>>>(qW2, cW2, qb2, cb2, qw2m, cw2m, b2m);
  enso_kernel<<<64, 256, 0, stream>>>(x, tW1, tb1, tW2, tb2, hW1, hb1, hW2, hb2, cT, cH);
  convert_x<<<8192, 256, 0, stream>>>((const float4*)x, (uint2*)xb);
  gemm_kernel<<<dim3(128, 12), 256, 0, stream>>>(xb, WT, qb1, cb1, qw2m, cw2m, out, rowadd);
  finalize<<<8192, 256, 0, stream>>>(out, rowadd, b2m, cT, cH);
}

// Round 2
// 188.543 us; speedup vs baseline: 1.0750x; 1.0750x over previous
//
#include <hip/hip_runtime.h>

// ---------------------------------------------------------------------------
// out[b,i] = (x@L^T)[b,i] + quad_mean[b] + cubic_mean[b] + (i==0)*cT[b] + (i==1)*cH[b]
// quad_mean[b] = sum_h relu(x@qW1 + qb1)[b,h] * colmean(qW2)[h] + mean(qb2)
//
// Round 2: (a) m97-style global_load_lds(16B) staging in the GEMM main loop;
// (b) two-phase GEMM (nl_gemm -> rowadd, then lin_gemm folds rowadd+enso into
// its epilogue) eliminating the 128MB finalize RMW; (c) prep kernels fused.
// ---------------------------------------------------------------------------

#define OMEGA_F 0.5235987755982988f

typedef __attribute__((ext_vector_type(8))) short short8;
typedef __attribute__((ext_vector_type(4))) float f32x4;

__device__ __forceinline__ unsigned short f2bf(float f) {
  union { float f; unsigned int u; } a;
  a.f = f;
  unsigned int u = a.u;
  return (unsigned short)((u + 0x7fffu + ((u >> 16) & 1u)) >> 16);
}

// async global -> LDS, 16 B per lane; LDS dst = wave-uniform base + lane*16
__device__ __forceinline__ void gload16(const void* g, void* l) {
  __builtin_amdgcn_global_load_lds(
      (const __attribute__((address_space(1))) unsigned int*)g,
      (__attribute__((address_space(3))) unsigned int*)l, 16, 0, 0);
}

// ---- prep: WcatT (1536x512 bf16 n-major) + W2 col-means + b2 means ---------
__global__ void prep_kernel(const float* __restrict__ fc, const float* __restrict__ qW1,
                            const float* __restrict__ cW1, const float* __restrict__ t,
                            const float* __restrict__ qW2, const float* __restrict__ cW2,
                            const float* __restrict__ qb2, const float* __restrict__ cb2,
                            unsigned short* __restrict__ WT,
                            float* __restrict__ qw2m, float* __restrict__ cw2m,
                            float* __restrict__ b2m) {
  int b = blockIdx.x, tdx = threadIdx.x;
  if (b < 3072) {
    int idx = b * 256 + tdx;  // 0 .. 1536*512-1
    int n = idx >> 9;
    int k = idx & 511;
    float v;
    if (n < 512) {
      float th = OMEGA_F * t[0];
      float s1, c1, s2, c2;
      sincosf(th, &s1, &c1);
      sincosf(2.0f * th, &s2, &c2);
      const float* p = fc + ((size_t)n * 512 + k) * 5;
      v = p[0] + p[1] * c1 + p[2] * s1 + p[3] * c2 + p[4] * s2;
    } else if (n < 1024) {
      v = qW1[(size_t)k * 512 + (n - 512)];
    } else {
      v = cW1[(size_t)k * 512 + (n - 1024)];
    }
    WT[idx] = f2bf(v);
  } else if (b < 3076) {
    int bb = b - 3072;
    const float* W = (bb < 2) ? qW2 : cW2;
    float* o = (bb < 2) ? qw2m : cw2m;
    int h = (bb & 1) * 256 + tdx;
    const float4* row = (const float4*)(W + (size_t)h * 512);
    float s = 0.f;
    for (int i = 0; i < 128; ++i) { float4 v = row[i]; s += (v.x + v.y) + (v.z + v.w); }
    o[h] = s * (1.0f / 512.0f);
  } else {
    __shared__ float sm[256];
    sm[tdx] = qb2[tdx] + qb2[tdx + 256];
    __syncthreads();
    for (int w = 128; w > 0; w >>= 1) { if (tdx < w) sm[tdx] += sm[tdx + w]; __syncthreads(); }
    if (tdx == 0) b2m[0] = sm[0] * (1.0f / 512.0f);
    __syncthreads();
    sm[tdx] = cb2[tdx] + cb2[tdx + 256];
    __syncthreads();
    for (int w = 128; w > 0; w >>= 1) { if (tdx < w) sm[tdx] += sm[tdx + w]; __syncthreads(); }
    if (tdx == 0) b2m[1] = sm[0] * (1.0f / 512.0f);
  }
}

// ---- convert x -> bf16, plus enso MLPs + rowadd zeroing in tail blocks -----
__global__ void conv_enso(const float4* __restrict__ x4, uint2* __restrict__ xb,
                          const float* __restrict__ x,
                          const float* __restrict__ tW1, const float* __restrict__ tb1,
                          const float* __restrict__ tW2, const float* __restrict__ tb2,
                          const float* __restrict__ hW1, const float* __restrict__ hb1,
                          const float* __restrict__ hW2, const float* __restrict__ hb2,
                          float* __restrict__ cT, float* __restrict__ cH,
                          float* __restrict__ rowadd) {
  int b = blockIdx.x;
  if (b < 8192) {
    int i = b * 256 + threadIdx.x;  // 2097152 float4s
    float4 v = x4[i];
    uint2 r;
    r.x = (unsigned)f2bf(v.x) | ((unsigned)f2bf(v.y) << 16);
    r.y = (unsigned)f2bf(v.z) | ((unsigned)f2bf(v.w) << 16);
    xb[i] = r;
  } else {
    int row = (b - 8192) * 256 + threadIdx.x;  // 16384 rows
    rowadd[row] = 0.f;
    float T = x[(size_t)row * 512];
    float H = x[(size_t)row * 512 + 1];
    float fT[5] = {T, H, T * T, T * H, T * T * T};
    float fH[5] = {T, H, T * T, T * H, T * H * H};
    float sT = tb2[0], sH = hb2[0];
#pragma unroll 4
    for (int e = 0; e < 32; ++e) {
      float a1 = tb1[e], a2 = hb1[e];
#pragma unroll
      for (int f = 0; f < 5; ++f) {
        a1 += fT[f] * tW1[f * 32 + e];
        a2 += fH[f] * hW1[f * 32 + e];
      }
      sT += fmaxf(a1, 0.f) * tW2[e];
      sH += fmaxf(a2, 0.f) * hW2[e];
    }
    cT[row] = sT;
    cH[row] = sH;
  }
}

// ---------------------------------------------------------------------------
// Shared GEMM main loop (128x128 tile, BK=32, 4 waves 2x2, 16x16x32 bf16),
// m97-style: global_load_lds dwordx4 staging, 2 barriers / k-step.
// Each wave stages chunks {w, w+4} of A and B; chunk c = rows 16c..16c+15,
// LDS layout row-major 128x32 (lane order matches DMA lane*16B rule).
// ---------------------------------------------------------------------------
#define GEMM_MAINLOOP(A_, Bt_)                                                    \
  __shared__ unsigned short As[128 * 32];                                         \
  __shared__ unsigned short Bs[128 * 32];                                         \
  const int tid = threadIdx.x;                                                    \
  const int lane = tid & 63;                                                      \
  const int wave = tid >> 6;                                                      \
  const int wm = wave & 1;                                                        \
  const int wn = wave >> 1;                                                       \
  const int m_base = blockIdx.x * 128;                                            \
  const int n_base = blockIdx.y * 128;                                            \
  const int lrow = lane & 15;                                                     \
  const int lk = (lane >> 4) * 8;                                                 \
  const int sr0 = wave * 16 + (lane >> 2);                                        \
  const int scg = (lane & 3) * 8;                                                 \
  const unsigned short* gA0 = A_ + (size_t)(m_base + sr0) * 512 + scg;            \
  const unsigned short* gA1 = gA0 + 64 * 512;                                     \
  const unsigned short* gB0 = Bt_ + (size_t)(n_base + sr0) * 512 + scg;           \
  const unsigned short* gB1 = gB0 + 64 * 512;                                     \
  unsigned short* lA0 = As + wave * 512;                                          \
  unsigned short* lA1 = As + (wave + 4) * 512;                                    \
  unsigned short* lB0 = Bs + wave * 512;                                          \
  unsigned short* lB1 = Bs + (wave + 4) * 512;                                    \
  f32x4 acc[4][4];                                                                \
  _Pragma("unroll") for (int i = 0; i < 4; ++i)                                   \
      _Pragma("unroll") for (int j = 0; j < 4; ++j)                               \
          acc[i][j] = (f32x4){0.f, 0.f, 0.f, 0.f};                                \
  for (int k0 = 0; k0 < 512; k0 += 32) {                                          \
    gload16(gA0, lA0);                                                            \
    gload16(gA1, lA1);                                                            \
    gload16(gB0, lB0);                                                            \
    gload16(gB1, lB1);                                                            \
    gA0 += 32; gA1 += 32; gB0 += 32; gB1 += 32;                                   \
    __syncthreads();                                                              \
    short8 af[4], bfr[4];                                                         \
    _Pragma("unroll") for (int i = 0; i < 4; ++i)                                 \
        af[i] = *(const short8*)(&As[(wm * 64 + i * 16 + lrow) * 32 + lk]);       \
    _Pragma("unroll") for (int j = 0; j < 4; ++j)                                 \
        bfr[j] = *(const short8*)(&Bs[(wn * 64 + j * 16 + lrow) * 32 + lk]);      \
    _Pragma("unroll") for (int i = 0; i < 4; ++i)                                 \
        _Pragma("unroll") for (int j = 0; j < 4; ++j)                             \
            acc[i][j] = __builtin_amdgcn_mfma_f32_16x16x32_bf16(af[i], bfr[j],    \
                                                                acc[i][j], 0, 0, 0); \
    __syncthreads();                                                              \
  }

// ---- phase 1: x @ [qW1 | cW1] -> relu.w2m row reduction -> rowadd ----------
__global__ __launch_bounds__(256) void nl_gemm(
    const unsigned short* __restrict__ A,    // 16384 x 512 bf16
    const unsigned short* __restrict__ Bt,   // 1024 x 512 bf16 (WT rows 512..1535)
    const float* __restrict__ qb1, const float* __restrict__ cb1,
    const float* __restrict__ qw2m, const float* __restrict__ cw2m,
    float* __restrict__ rowadd) {
  GEMM_MAINLOOP(A, Bt)
  // C/D: col = lane&15, row = (lane>>4)*4 + reg (m89/m91)
  const int rbase = m_base + wm * 64 + (lane >> 4) * 4;
  const bool isq = (blockIdx.y < 4);
  const float* b1 = isq ? qb1 : cb1;
  const float* w2m = isq ? qw2m : cw2m;
  const int cb0 = (isq ? n_base : n_base - 512) + wn * 64 + lrow;
  float rs[4][4];
#pragma unroll
  for (int i = 0; i < 4; ++i)
#pragma unroll
    for (int r = 0; r < 4; ++r) rs[i][r] = 0.f;
#pragma unroll
  for (int j = 0; j < 4; ++j) {
    int col = cb0 + j * 16;
    float bb = b1[col];
    float ww = w2m[col];
#pragma unroll
    for (int i = 0; i < 4; ++i)
#pragma unroll
      for (int r = 0; r < 4; ++r)
        rs[i][r] += fmaxf(acc[i][j][r] + bb, 0.f) * ww;
  }
#pragma unroll
  for (int i = 0; i < 4; ++i)
#pragma unroll
    for (int r = 0; r < 4; ++r) {
      float v = rs[i][r];
      v += __shfl_xor(v, 1, 64);
      v += __shfl_xor(v, 2, 64);
      v += __shfl_xor(v, 4, 64);
      v += __shfl_xor(v, 8, 64);
      if (lrow == 0) atomicAdd(&rowadd[rbase + i * 16 + r], v);
    }
}

// ---- phase 2: x @ L^T, epilogue folds rowadd + b2 means + enso -> out ------
__global__ __launch_bounds__(256) void lin_gemm(
    const unsigned short* __restrict__ A,    // 16384 x 512 bf16
    const unsigned short* __restrict__ Bt,   // 512 x 512 bf16 (WT rows 0..511)
    const float* __restrict__ rowadd, const float* __restrict__ b2m,
    const float* __restrict__ cT, const float* __restrict__ cH,
    float* __restrict__ out) {
  GEMM_MAINLOOP(A, Bt)
  const int rbase = m_base + wm * 64 + (lane >> 4) * 4;
  const float b2s = b2m[0] + b2m[1];
  float ra[4][4];
#pragma unroll
  for (int i = 0; i < 4; ++i)
#pragma unroll
    for (int r = 0; r < 4; ++r) ra[i][r] = rowadd[rbase + i * 16 + r] + b2s;
#pragma unroll
  for (int j = 0; j < 4; ++j) {
    int col = n_base + wn * 64 + j * 16 + lrow;
#pragma unroll
    for (int i = 0; i < 4; ++i)
#pragma unroll
      for (int r = 0; r < 4; ++r) {
        int row = rbase + i * 16 + r;
        float v = acc[i][j][r] + ra[i][r];
        if (col == 0) v += cT[row];
        if (col == 1) v += cH[row];
        out[(size_t)row * 512 + col] = v;
      }
  }
}

extern "C" void kernel_launch(void* const* d_in, const int* in_sizes, int n_in,
                              void* d_out, int out_size, void* d_ws, size_t ws_size,
                              hipStream_t stream) {
  const float* x   = (const float*)d_in[0];
  const float* t   = (const float*)d_in[1];
  const float* fc  = (const float*)d_in[2];
  const float* qW1 = (const float*)d_in[3];
  const float* qb1 = (const float*)d_in[4];
  const float* qW2 = (const float*)d_in[5];
  const float* qb2 = (const float*)d_in[6];
  const float* cW1 = (const float*)d_in[7];
  const float* cb1 = (const float*)d_in[8];
  const float* cW2 = (const float*)d_in[9];
  const float* cb2 = (const float*)d_in[10];
  const float* tW1 = (const float*)d_in[11];
  const float* tb1 = (const float*)d_in[12];
  const float* tW2 = (const float*)d_in[13];
  const float* tb2 = (const float*)d_in[14];
  const float* hW1 = (const float*)d_in[15];
  const float* hb1 = (const float*)d_in[16];
  const float* hW2 = (const float*)d_in[17];
  const float* hb2 = (const float*)d_in[18];
  float* out = (float*)d_out;

  // workspace layout (bytes); total ~18.6 MB
  char* ws = (char*)d_ws;
  unsigned short* WT = (unsigned short*)(ws);              // 1536*512*2   = 1,572,864
  unsigned short* xb = (unsigned short*)(ws + 1572864);    // 16384*512*2  = 16,777,216
  float* qw2m   = (float*)(ws + 18350080);                 // 512*4
  float* cw2m   = (float*)(ws + 18352128);                 // 512*4
  float* b2m    = (float*)(ws + 18354176);                 // 2*4 (pad)
  float* cT     = (float*)(ws + 18354432);                 // 16384*4
  float* cH     = (float*)(ws + 18419968);                 // 16384*4
  float* rowadd = (float*)(ws + 18485504);                 // 16384*4 -> ends 18,551,040

  prep_kernel<<<3077, 256, 0, stream>>>(fc, qW1, cW1, t, qW2, cW2, qb2, cb2,
                                        WT, qw2m, cw2m, b2m);
  conv_enso<<<8256, 256, 0, stream>>>((const float4*)x, (uint2*)xb, x,
                                      tW1, tb1, tW2, tb2, hW1, hb1, hW2, hb2,
                                      cT, cH, rowadd);
  nl_gemm<<<dim3(128, 8), 256, 0, stream>>>(xb, WT + (size_t)512 * 512,
                                            qb1, cb1, qw2m, cw2m, rowadd);
  lin_gemm<<<dim3(128, 4), 256, 0, stream>>>(xb, WT, rowadd, b2m, cT, cH, out);
}